// Round 8
// baseline (110.949 us; speedup 1.0000x reference)
//
#include <hip/hip_runtime.h>

// Problem: B=4, C=19, H=1024, W=1024, N=500000
// out = mean_n [ log(sum_j exp(p_j)) - p_label ],  p = softmax(predict[b,:,r,c])
//
// Round-8 structure (count-table formulation):
//   mean = (1/N) * sum_pos count[pos] * nll[pos]
//   (M0) clear 4MB uint8 count table
//   (M1) atomic scatter-increment counts from loc arrays (packed-byte atomics,
//        integer -> deterministic; max cell count ~10 << 255)
//   (A)  stream predict/target; count>0 is the predication (suppresses 64B
//        line fetch for ~15% untouched chunks), count is the gather weight;
//        block tree-reduce -> partial[block]
//   (C)  finalize: double-accumulate partials, divide by N.
// This deletes the 16MB table write + 16MB random table read + kernel B of
// rounds 3-7, and gets round-7's predication with no separate mask build.
//
// Lessons kept: scalar x[19] (~24 VGPR, 32 waves/CU) beats float4 (rounds
// 5/6: occupancy cliff); no nontemporal hints (round 5); integer inputs all
// arrive as int32 (round 1).

#define CCH 19
#define BLOCK 256
#define POS_BITS 20               // H*W = 1<<20
#define TOTAL_POS (4 << POS_BITS) // B * H * W = 4M
#define NBLK_A (TOTAL_POS / BLOCK)

__device__ __forceinline__ float nll_compute(float* __restrict__ x, int label)
{
    float m = x[0];
    #pragma unroll
    for (int j = 1; j < CCH; ++j) m = fmaxf(m, x[j]);

    float s = 0.0f, e_label = 0.0f;
    #pragma unroll
    for (int j = 0; j < CCH; ++j) {
        float e = __expf(x[j] - m);
        s += e;
        if (j == label) e_label = e;   // static j vs runtime label -> cndmask
        x[j] = e;
    }
    float inv = 1.0f / s;

    float s2 = 0.0f;
    #pragma unroll
    for (int j = 0; j < CCH; ++j) s2 += __expf(x[j] * inv);

    return __logf(s2) - e_label * inv;
}

// ---- M0: clear count table (d_ws poisoned 0xAA; zero every call) ----
__global__ __launch_bounds__(BLOCK) void clear_counts(unsigned int* __restrict__ cnt32)
{
    int i = blockIdx.x * blockDim.x + threadIdx.x;   // TOTAL_POS/4 words
    cnt32[i] = 0u;
}

// ---- M1: packed-byte atomic scatter-increment ----
__global__ __launch_bounds__(BLOCK) void build_counts(
    const int* __restrict__ loc_b,
    const int* __restrict__ loc_row,
    const int* __restrict__ loc_col,
    unsigned int* __restrict__ cnt32,
    int n)
{
    int i = blockIdx.x * blockDim.x + threadIdx.x;
    if (i < n) {
        int idx = (loc_b[i] << POS_BITS) + (loc_row[i] << 10) + loc_col[i];
        atomicAdd(&cnt32[idx >> 2], 1u << ((idx & 3) << 3));
    }
}

// ---- A: streamed weighted nll reduction (1 thread = 1 position) ----
__global__ __launch_bounds__(BLOCK) void nll_count_reduce(
    const float* __restrict__ predict,
    const int* __restrict__ target,
    const unsigned char* __restrict__ counts,
    float* __restrict__ partial)
{
    int i = blockIdx.x * blockDim.x + threadIdx.x;   // coalesced position index
    int cnt = counts[i];                             // 64B/wave, coalesced
    float contrib = 0.0f;
    if (cnt) {                                       // lane-predicated: untouched
        int b = i >> POS_BITS;                       // 64B chunks never fetched
        int pos = i & ((1 << POS_BITS) - 1);
        const float* base = predict + (((size_t)b * CCH) << POS_BITS) + (size_t)pos;
        float x[CCH];
        #pragma unroll
        for (int j = 0; j < CCH; ++j) x[j] = base[(size_t)j << POS_BITS];
        contrib = (float)cnt * nll_compute(x, target[i]);
    }

    __shared__ float red[BLOCK];
    red[threadIdx.x] = contrib;
    __syncthreads();
    #pragma unroll
    for (int off = BLOCK / 2; off > 0; off >>= 1) {
        if (threadIdx.x < off) red[threadIdx.x] += red[threadIdx.x + off];
        __syncthreads();
    }
    if (threadIdx.x == 0) partial[blockIdx.x] = red[0];
}

// ---- fallback: direct random gather (round-2 path), used if ws too small ----
__global__ __launch_bounds__(BLOCK) void partial_loss_gather(
    const float* __restrict__ predict,
    const int* __restrict__ target,
    const int* __restrict__ loc_b,
    const int* __restrict__ loc_row,
    const int* __restrict__ loc_col,
    float* __restrict__ partial,
    int n)
{
    int i = blockIdx.x * blockDim.x + threadIdx.x;
    float nll = 0.0f;
    if (i < n) {
        int b = loc_b[i];
        int pos = (loc_row[i] << 10) + loc_col[i];
        const float* base = predict + (((size_t)b * CCH) << POS_BITS) + (size_t)pos;
        int label = target[((size_t)b << POS_BITS) + (size_t)pos];
        float x[CCH];
        #pragma unroll
        for (int j = 0; j < CCH; ++j) x[j] = base[(size_t)j << POS_BITS];
        nll = nll_compute(x, label);
    }
    __shared__ float red[BLOCK];
    red[threadIdx.x] = nll;
    __syncthreads();
    #pragma unroll
    for (int off = BLOCK / 2; off > 0; off >>= 1) {
        if (threadIdx.x < off) red[threadIdx.x] += red[threadIdx.x + off];
        __syncthreads();
    }
    if (threadIdx.x == 0) partial[blockIdx.x] = red[0];
}

__global__ __launch_bounds__(BLOCK) void partial_loss_finalize(
    const float* __restrict__ partial,
    int nparts,
    float* __restrict__ out,
    float inv_n)
{
    __shared__ double red[BLOCK];
    double acc = 0.0;
    for (int i = threadIdx.x; i < nparts; i += BLOCK) acc += (double)partial[i];
    red[threadIdx.x] = acc;
    __syncthreads();
    #pragma unroll
    for (int off = BLOCK / 2; off > 0; off >>= 1) {
        if (threadIdx.x < off) red[threadIdx.x] += red[threadIdx.x + off];
        __syncthreads();
    }
    if (threadIdx.x == 0) out[0] = (float)(red[0] * (double)inv_n);
}

extern "C" void kernel_launch(void* const* d_in, const int* in_sizes, int n_in,
                              void* d_out, int out_size, void* d_ws, size_t ws_size,
                              hipStream_t stream)
{
    const float* predict = (const float*)d_in[0];
    const int*   target  = (const int*)d_in[1];
    const int*   loc_b   = (const int*)d_in[2];
    const int*   loc_row = (const int*)d_in[3];
    const int*   loc_col = (const int*)d_in[4];
    float* out = (float*)d_out;

    int n = in_sizes[2];                         // N = 500000
    int nblocks = (n + BLOCK - 1) / BLOCK;       // 1954 (scatter/fallback grid)

    size_t count_bytes   = (size_t)TOTAL_POS;                  // 4 MB (uint8)
    size_t partial_bytes = (size_t)NBLK_A * sizeof(float);     // 64 KB

    if (ws_size >= count_bytes + partial_bytes) {
        unsigned int* cnt32   = (unsigned int*)d_ws;
        float*        partial = (float*)((char*)d_ws + count_bytes);

        clear_counts<<<TOTAL_POS / 4 / BLOCK, BLOCK, 0, stream>>>(cnt32);
        build_counts<<<nblocks, BLOCK, 0, stream>>>(loc_b, loc_row, loc_col, cnt32, n);
        nll_count_reduce<<<NBLK_A, BLOCK, 0, stream>>>(
            predict, target, (const unsigned char*)cnt32, partial);
        partial_loss_finalize<<<1, BLOCK, 0, stream>>>(
            partial, NBLK_A, out, 1.0f / (float)n);
    } else {
        float* partial = (float*)d_ws;
        partial_loss_gather<<<nblocks, BLOCK, 0, stream>>>(
            predict, target, loc_b, loc_row, loc_col, partial, n);
        partial_loss_finalize<<<1, BLOCK, 0, stream>>>(
            partial, nblocks, out, 1.0f / (float)n);
    }
}

// Round 9
// 96.272 us; speedup vs baseline: 1.1524x; 1.1524x over previous
//
#include <hip/hip_runtime.h>

// Problem: B=4, C=19, H=1024, W=1024, N=500000
// out = mean_n [ log(sum_j exp(p_j)) - p_label ],  p = softmax(predict[b,:,r,c])
//
// Round-9 structure = round 3 (best, 87.8us) with kernel A restructured:
//   (A) LDS-tiled streaming pass: each block stages 19ch x 512pos through
//       38KB LDS with float4 loads (2KB contiguous burst per channel per
//       block, vs 19 interleaved 256B runs at 4MB power-of-2 stride -> fixes
//       DRAM page/channel aliasing that held A at ~5 TB/s), computes nll for
//       all 4M positions into a 16MB table in d_ws.
//   (B) random 4B gather from table + block reduce  (unchanged)
//   (C) finalize                                     (unchanged)
//
// Lessons kept: NO mask/predication (rounds 7/8: build cost >= savings; random
// atomics ~50ns each), NO register-array float4 (rounds 5/6: VGPR cliff), NO
// nontemporal hints (round 5), integer inputs all arrive int32 (round 1).

#define CCH 19
#define BLOCK 256
#define TILE 512                  // positions per block tile
#define POS_BITS 20               // H*W = 1<<20
#define TOTAL_POS (4 << POS_BITS) // B * H * W = 4M
#define NV4 (CCH * TILE / 4)      // 2432 float4 loads per tile

__device__ __forceinline__ float nll_compute(float* __restrict__ x, int label)
{
    float m = x[0];
    #pragma unroll
    for (int j = 1; j < CCH; ++j) m = fmaxf(m, x[j]);

    float s = 0.0f, e_label = 0.0f;
    #pragma unroll
    for (int j = 0; j < CCH; ++j) {
        float e = __expf(x[j] - m);
        s += e;
        if (j == label) e_label = e;   // static j vs runtime label -> cndmask
        x[j] = e;
    }
    float inv = 1.0f / s;

    float s2 = 0.0f;
    #pragma unroll
    for (int j = 0; j < CCH; ++j) s2 += __expf(x[j] * inv);

    return __logf(s2) - e_label * inv;
}

// ---- kernel A: LDS-tiled nll table ----
// grid = TOTAL_POS/TILE = 8192 blocks; TILE divides H*W so a tile never
// straddles the batch dimension.
__global__ __launch_bounds__(BLOCK) void nll_table_tiled(
    const float* __restrict__ predict,
    const int* __restrict__ target,
    float* __restrict__ table)
{
    __shared__ float lds[CCH * TILE];              // 38 KB -> 4 blocks/CU
    int i0 = blockIdx.x * TILE;                    // flat position base
    int b = i0 >> POS_BITS;
    int pos0 = i0 & ((1 << POS_BITS) - 1);
    const float* pbase = predict + (((size_t)b * CCH) << POS_BITS) + (size_t)pos0;

    // stage 19 channels x 512 floats: one 2KB contiguous burst per channel
    #pragma unroll
    for (int it = 0; it < (NV4 + BLOCK - 1) / BLOCK; ++it) {
        int f = it * BLOCK + threadIdx.x;          // float4 slot in [0, 2432)
        if (f < NV4) {
            int ch = f >> 7;                       // 128 float4 per channel
            int q  = f & 127;
            float4 v = *(const float4*)(pbase + ((size_t)ch << POS_BITS) + (q << 2));
            *(float4*)&lds[ch * TILE + (q << 2)] = v;
        }
    }
    __syncthreads();

    // compute 2 positions per thread; LDS reads are lane-stride-4B (conflict-free)
    #pragma unroll
    for (int p = 0; p < TILE / BLOCK; ++p) {
        int pp = threadIdx.x + p * BLOCK;
        float x[CCH];
        #pragma unroll
        for (int j = 0; j < CCH; ++j) x[j] = lds[j * TILE + pp];
        table[i0 + pp] = nll_compute(x, target[i0 + pp]);
    }
}

// ---- kernel B: random 4B gather from table + block reduce (round 3) ----
__global__ __launch_bounds__(BLOCK) void table_gather_kernel(
    const float* __restrict__ table,
    const int* __restrict__ loc_b,
    const int* __restrict__ loc_row,
    const int* __restrict__ loc_col,
    float* __restrict__ partial,
    int n)
{
    int i = blockIdx.x * blockDim.x + threadIdx.x;
    float nll = 0.0f;
    if (i < n) {
        int idx = (loc_b[i] << POS_BITS) + (loc_row[i] << 10) + loc_col[i];
        nll = table[idx];
    }
    __shared__ float red[BLOCK];
    red[threadIdx.x] = nll;
    __syncthreads();
    #pragma unroll
    for (int off = BLOCK / 2; off > 0; off >>= 1) {
        if (threadIdx.x < off) red[threadIdx.x] += red[threadIdx.x + off];
        __syncthreads();
    }
    if (threadIdx.x == 0) partial[blockIdx.x] = red[0];
}

// ---- fallback: direct random gather (round-2 path), used if ws too small ----
__global__ __launch_bounds__(BLOCK) void partial_loss_gather(
    const float* __restrict__ predict,
    const int* __restrict__ target,
    const int* __restrict__ loc_b,
    const int* __restrict__ loc_row,
    const int* __restrict__ loc_col,
    float* __restrict__ partial,
    int n)
{
    int i = blockIdx.x * blockDim.x + threadIdx.x;
    float nll = 0.0f;
    if (i < n) {
        int b = loc_b[i];
        int pos = (loc_row[i] << 10) + loc_col[i];
        const float* base = predict + (((size_t)b * CCH) << POS_BITS) + (size_t)pos;
        int label = target[((size_t)b << POS_BITS) + (size_t)pos];
        float x[CCH];
        #pragma unroll
        for (int j = 0; j < CCH; ++j) x[j] = base[(size_t)j << POS_BITS];
        nll = nll_compute(x, label);
    }
    __shared__ float red[BLOCK];
    red[threadIdx.x] = nll;
    __syncthreads();
    #pragma unroll
    for (int off = BLOCK / 2; off > 0; off >>= 1) {
        if (threadIdx.x < off) red[threadIdx.x] += red[threadIdx.x + off];
        __syncthreads();
    }
    if (threadIdx.x == 0) partial[blockIdx.x] = red[0];
}

__global__ __launch_bounds__(BLOCK) void partial_loss_finalize(
    const float* __restrict__ partial,
    int nparts,
    float* __restrict__ out,
    float inv_n)
{
    __shared__ double red[BLOCK];
    double acc = 0.0;
    for (int i = threadIdx.x; i < nparts; i += BLOCK) acc += (double)partial[i];
    red[threadIdx.x] = acc;
    __syncthreads();
    #pragma unroll
    for (int off = BLOCK / 2; off > 0; off >>= 1) {
        if (threadIdx.x < off) red[threadIdx.x] += red[threadIdx.x + off];
        __syncthreads();
    }
    if (threadIdx.x == 0) out[0] = (float)(red[0] * (double)inv_n);
}

extern "C" void kernel_launch(void* const* d_in, const int* in_sizes, int n_in,
                              void* d_out, int out_size, void* d_ws, size_t ws_size,
                              hipStream_t stream)
{
    const float* predict = (const float*)d_in[0];
    const int*   target  = (const int*)d_in[1];
    const int*   loc_b   = (const int*)d_in[2];
    const int*   loc_row = (const int*)d_in[3];
    const int*   loc_col = (const int*)d_in[4];
    float* out = (float*)d_out;

    int n = in_sizes[2];                         // N = 500000
    int nblocks = (n + BLOCK - 1) / BLOCK;       // 1954

    size_t table_bytes   = (size_t)TOTAL_POS * sizeof(float);   // 16 MB
    size_t partial_bytes = (size_t)nblocks * sizeof(float);

    if (ws_size >= table_bytes + partial_bytes) {
        float* table   = (float*)d_ws;
        float* partial = (float*)((char*)d_ws + table_bytes);

        nll_table_tiled<<<TOTAL_POS / TILE, BLOCK, 0, stream>>>(
            predict, target, table);
        table_gather_kernel<<<nblocks, BLOCK, 0, stream>>>(
            table, loc_b, loc_row, loc_col, partial, n);
        partial_loss_finalize<<<1, BLOCK, 0, stream>>>(
            partial, nblocks, out, 1.0f / (float)n);
    } else {
        float* partial = (float*)d_ws;
        partial_loss_gather<<<nblocks, BLOCK, 0, stream>>>(
            predict, target, loc_b, loc_row, loc_col, partial, n);
        partial_loss_finalize<<<1, BLOCK, 0, stream>>>(
            partial, nblocks, out, 1.0f / (float)n);
    }
}

// Round 10
// 84.976 us; speedup vs baseline: 1.3056x; 1.1329x over previous
//
#include <hip/hip_runtime.h>

// Problem: B=4, C=19, H=1024, W=1024, N=500000
// out = mean_n [ log(sum_j exp(p_j)) - p_label ],  p = softmax(predict[b,:,r,c])
//
// Round-10 = round-9's LDS-tiled kernel A with the occupancy confound removed:
//   TILE 512->256 => LDS 38KB->19KB => 8 blocks/CU (152KB/160KB) = 32 waves/CU,
//   SAME occupancy as round-3 scalar. Single-variable A/B:
//     vs R3: access pattern only (1KB float4 bursts vs 256B scalar runs)
//     vs R9: occupancy only (32 vs 16 waves/CU)
//   (B) random 4B gather from table + block reduce  (unchanged from R3)
//   (C) finalize                                     (unchanged)
//
// Lessons kept: NO mask/predication (R7/R8), NO register-array float4 (R5/R6
// VGPR cliff), NO nontemporal hints (R5), NO random atomics (R8), integer
// inputs all arrive int32 (R1).

#define CCH 19
#define BLOCK 256
#define TILE 256                  // positions per block tile (= BLOCK)
#define POS_BITS 20               // H*W = 1<<20
#define TOTAL_POS (4 << POS_BITS) // B * H * W = 4M
#define NV4 (CCH * TILE / 4)      // 1216 float4 loads per tile

__device__ __forceinline__ float nll_compute(float* __restrict__ x, int label)
{
    float m = x[0];
    #pragma unroll
    for (int j = 1; j < CCH; ++j) m = fmaxf(m, x[j]);

    float s = 0.0f, e_label = 0.0f;
    #pragma unroll
    for (int j = 0; j < CCH; ++j) {
        float e = __expf(x[j] - m);
        s += e;
        if (j == label) e_label = e;   // static j vs runtime label -> cndmask
        x[j] = e;
    }
    float inv = 1.0f / s;

    float s2 = 0.0f;
    #pragma unroll
    for (int j = 0; j < CCH; ++j) s2 += __expf(x[j] * inv);

    return __logf(s2) - e_label * inv;
}

// ---- kernel A: LDS-tiled nll table, 19KB LDS, full occupancy ----
// grid = TOTAL_POS/TILE = 16384 blocks; TILE divides H*W so a tile never
// straddles the batch dimension.
__global__ __launch_bounds__(BLOCK) void nll_table_tiled256(
    const float* __restrict__ predict,
    const int* __restrict__ target,
    float* __restrict__ table)
{
    __shared__ float lds[CCH * TILE];              // 19 KB -> 8 blocks/CU
    int i0 = blockIdx.x * TILE;                    // flat position base
    int b = i0 >> POS_BITS;
    int pos0 = i0 & ((1 << POS_BITS) - 1);
    const float* pbase = predict + (((size_t)b * CCH) << POS_BITS) + (size_t)pos0;

    // stage 19 channels x 256 floats: one 1KB contiguous float4 burst/channel
    #pragma unroll
    for (int it = 0; it < (NV4 + BLOCK - 1) / BLOCK; ++it) {
        int f = it * BLOCK + threadIdx.x;          // float4 slot in [0, 1216)
        if (f < NV4) {
            int ch = f >> 6;                       // 64 float4 per channel
            int q  = f & 63;
            float4 v = *(const float4*)(pbase + ((size_t)ch << POS_BITS) + (q << 2));
            *(float4*)&lds[ch * TILE + (q << 2)] = v;
        }
    }
    __syncthreads();

    // 1 position per thread; LDS reads lane-stride-4B (2-way aliasing = free)
    int pp = threadIdx.x;
    float x[CCH];
    #pragma unroll
    for (int j = 0; j < CCH; ++j) x[j] = lds[j * TILE + pp];
    table[i0 + pp] = nll_compute(x, target[i0 + pp]);
}

// ---- kernel B: random 4B gather from table + block reduce (round 3) ----
__global__ __launch_bounds__(BLOCK) void table_gather_kernel(
    const float* __restrict__ table,
    const int* __restrict__ loc_b,
    const int* __restrict__ loc_row,
    const int* __restrict__ loc_col,
    float* __restrict__ partial,
    int n)
{
    int i = blockIdx.x * blockDim.x + threadIdx.x;
    float nll = 0.0f;
    if (i < n) {
        int idx = (loc_b[i] << POS_BITS) + (loc_row[i] << 10) + loc_col[i];
        nll = table[idx];
    }
    __shared__ float red[BLOCK];
    red[threadIdx.x] = nll;
    __syncthreads();
    #pragma unroll
    for (int off = BLOCK / 2; off > 0; off >>= 1) {
        if (threadIdx.x < off) red[threadIdx.x] += red[threadIdx.x + off];
        __syncthreads();
    }
    if (threadIdx.x == 0) partial[blockIdx.x] = red[0];
}

// ---- fallback: direct random gather (round-2 path), used if ws too small ----
__global__ __launch_bounds__(BLOCK) void partial_loss_gather(
    const float* __restrict__ predict,
    const int* __restrict__ target,
    const int* __restrict__ loc_b,
    const int* __restrict__ loc_row,
    const int* __restrict__ loc_col,
    float* __restrict__ partial,
    int n)
{
    int i = blockIdx.x * blockDim.x + threadIdx.x;
    float nll = 0.0f;
    if (i < n) {
        int b = loc_b[i];
        int pos = (loc_row[i] << 10) + loc_col[i];
        const float* base = predict + (((size_t)b * CCH) << POS_BITS) + (size_t)pos;
        int label = target[((size_t)b << POS_BITS) + (size_t)pos];
        float x[CCH];
        #pragma unroll
        for (int j = 0; j < CCH; ++j) x[j] = base[(size_t)j << POS_BITS];
        nll = nll_compute(x, label);
    }
    __shared__ float red[BLOCK];
    red[threadIdx.x] = nll;
    __syncthreads();
    #pragma unroll
    for (int off = BLOCK / 2; off > 0; off >>= 1) {
        if (threadIdx.x < off) red[threadIdx.x] += red[threadIdx.x + off];
        __syncthreads();
    }
    if (threadIdx.x == 0) partial[blockIdx.x] = red[0];
}

__global__ __launch_bounds__(BLOCK) void partial_loss_finalize(
    const float* __restrict__ partial,
    int nparts,
    float* __restrict__ out,
    float inv_n)
{
    __shared__ double red[BLOCK];
    double acc = 0.0;
    for (int i = threadIdx.x; i < nparts; i += BLOCK) acc += (double)partial[i];
    red[threadIdx.x] = acc;
    __syncthreads();
    #pragma unroll
    for (int off = BLOCK / 2; off > 0; off >>= 1) {
        if (threadIdx.x < off) red[threadIdx.x] += red[threadIdx.x + off];
        __syncthreads();
    }
    if (threadIdx.x == 0) out[0] = (float)(red[0] * (double)inv_n);
}

extern "C" void kernel_launch(void* const* d_in, const int* in_sizes, int n_in,
                              void* d_out, int out_size, void* d_ws, size_t ws_size,
                              hipStream_t stream)
{
    const float* predict = (const float*)d_in[0];
    const int*   target  = (const int*)d_in[1];
    const int*   loc_b   = (const int*)d_in[2];
    const int*   loc_row = (const int*)d_in[3];
    const int*   loc_col = (const int*)d_in[4];
    float* out = (float*)d_out;

    int n = in_sizes[2];                         // N = 500000
    int nblocks = (n + BLOCK - 1) / BLOCK;       // 1954

    size_t table_bytes   = (size_t)TOTAL_POS * sizeof(float);   // 16 MB
    size_t partial_bytes = (size_t)nblocks * sizeof(float);

    if (ws_size >= table_bytes + partial_bytes) {
        float* table   = (float*)d_ws;
        float* partial = (float*)((char*)d_ws + table_bytes);

        nll_table_tiled256<<<TOTAL_POS / TILE, BLOCK, 0, stream>>>(
            predict, target, table);
        table_gather_kernel<<<nblocks, BLOCK, 0, stream>>>(
            table, loc_b, loc_row, loc_col, partial, n);
        partial_loss_finalize<<<1, BLOCK, 0, stream>>>(
            partial, nblocks, out, 1.0f / (float)n);
    } else {
        float* partial = (float*)d_ws;
        partial_loss_gather<<<nblocks, BLOCK, 0, stream>>>(
            predict, target, loc_b, loc_row, loc_col, partial, n);
        partial_loss_finalize<<<1, BLOCK, 0, stream>>>(
            partial, nblocks, out, 1.0f / (float)n);
    }
}